// Round 8
// baseline (257.456 us; speedup 1.0000x reference)
//
#include <hip/hip_runtime.h>

#define EPS 0.01f
#define B_ 8
#define T_ 4096
#define D_ 1024
#define TCHUNK 128
#define NBLK_T (T_ / TCHUNK)     // 32
#define NPROD (B_ * NBLK_T)      // 256 producer blocks
#define FLAG_MAGIC 0x7F3A2B1Cu

// Single launch, 272 blocks:
//   blocks 0..255   : producers — alpha + y=x@w (gated rows only) + mem partials
//   blocks 256..263 : bias-scan consumer for b = blk-256 (spin-waits on b's flags)
//   blocks 264..271 : mem-reduce consumer for b = blk-264
// Consumers start as soon as their b's 32 producers are done (per-block flags,
// release/acquire at agent scope) — overlaps finalize with producer tail and
// removes the second launch. 16 spinners << 256 CUs => no deadlock regardless
// of dispatch order (G16-safe: no ordering or coherence assumptions beyond
// device-scope atomics + fences).
__global__ __launch_bounds__(1024) void fused_kernel(
    const float* __restrict__ x, const float* __restrict__ w,
    const int* __restrict__ pad, const int* __restrict__ upd,
    float* __restrict__ y, float* __restrict__ mem_part,
    unsigned* __restrict__ flags,
    float* __restrict__ bias, float* __restrict__ mem) {
    const int blk = blockIdx.x;
    const int tid = threadIdx.x;           // 0..1023
    const int wave = tid >> 6;             // 0..15
    const int lane = tid & 63;

    if (blk < NPROD) {
        // ================= producer =================
        const int b = blk >> 5;            // 0..7
        const int bx = blk & 31;           // 0..31
        const int tbase = bx * TCHUNK;
        const int base = b * T_;

        // ---- gate prefix counts via shfl scan -> alpha_s[TCHUNK] ----
        __shared__ float alpha_s[TCHUNK];
        __shared__ int wtot[16];
        {
            const int4 pv = reinterpret_cast<const int4*>(pad + base)[tid];
            const int4 uv = reinterpret_cast<const int4*>(upd + base)[tid];
            int g[4];
            g[0] = (pv.x == 0 && uv.x != 0) ? 1 : 0;
            g[1] = (pv.y == 0 && uv.y != 0) ? 1 : 0;
            g[2] = (pv.z == 0 && uv.z != 0) ? 1 : 0;
            g[3] = (pv.w == 0 && uv.w != 0) ? 1 : 0;
            const int cnt = g[0] + g[1] + g[2] + g[3];

            int inc = cnt;                  // wave-inclusive scan, no barriers
            #pragma unroll
            for (int off = 1; off <= 32; off <<= 1) {
                int n = __shfl_up(inc, off);
                if (lane >= off) inc += n;
            }
            if (lane == 63) wtot[wave] = inc;
            __syncthreads();
            if (wave == 0 && lane < 16) {   // scan 16 wave totals
                int iv = wtot[lane];
                #pragma unroll
                for (int off = 1; off <= 8; off <<= 1) {
                    int n = __shfl_up(iv, off);
                    if (lane >= off) iv += n;
                }
                wtot[lane] = iv;
            }
            __syncthreads();
            const int total = wtot[15];
            int c = (wave > 0 ? wtot[wave - 1] : 0) + inc - cnt;  // exclusive
            const float L = -0.014499569695115089f;  // log2(0.99)
            #pragma unroll
            for (int i = 0; i < 4; ++i) {
                const int t = 4 * tid + i;
                c += g[i];
                if (t >= tbase && t < tbase + TCHUNK)
                    alpha_s[t - tbase] = g[i] ? EPS * exp2f((float)(total - c) * L) : 0.f;
            }
        }
        __syncthreads();

        float4 wv[4];
        #pragma unroll
        for (int k = 0; k < 4; ++k)
            wv[k] = *reinterpret_cast<const float4*>(w + k * 256 + lane * 4);

        float4 acc[4];
        #pragma unroll
        for (int k = 0; k < 4; ++k) acc[k] = make_float4(0.f, 0.f, 0.f, 0.f);

        for (int r = wave; r < TCHUNK; r += 16) {
            const float al = alpha_s[r];
            const int t = tbase + r;
            const float* rowp = x + ((size_t)b * T_ + t) * D_;
            if (al != 0.f) {                // non-gated row: no data needed
                float dot = 0.f;
                #pragma unroll
                for (int k = 0; k < 4; ++k) {
                    float4 v = *reinterpret_cast<const float4*>(rowp + k * 256 + lane * 4);
                    dot += v.x * wv[k].x + v.y * wv[k].y + v.z * wv[k].z + v.w * wv[k].w;
                    acc[k].x += al * v.x;
                    acc[k].y += al * v.y;
                    acc[k].z += al * v.z;
                    acc[k].w += al * v.w;
                }
                #pragma unroll
                for (int off = 32; off >= 1; off >>= 1)
                    dot += __shfl_xor(dot, off);
                if (lane == 0) y[b * T_ + t] = dot;
            }
        }

        // Block-level reduction of mem partials: [wave][d], column reads.
        __shared__ float part[16][D_];     // 64 KiB
        #pragma unroll
        for (int k = 0; k < 4; ++k)
            *reinterpret_cast<float4*>(&part[wave][k * 256 + lane * 4]) = acc[k];
        __syncthreads();
        float sum = 0.f;
        #pragma unroll
        for (int w2 = 0; w2 < 16; ++w2) sum += part[w2][tid];
        mem_part[((size_t)b * NBLK_T + bx) * D_ + tid] = sum;

        // ---- publish: all block stores visible, then flag (CUDA fence idiom) ----
        __threadfence();
        __syncthreads();
        if (tid == 0)
            __hip_atomic_store(&flags[blk], FLAG_MAGIC, __ATOMIC_RELEASE,
                               __HIP_MEMORY_SCOPE_AGENT);
        return;
    }

    // ================= consumers =================
    const int role = blk - NPROD;          // 0..15
    const int b = role & 7;

    // spin until all 32 producer blocks of this b have published
    if (wave == 0) {
        bool done = false;
        while (!done) {
            unsigned v = FLAG_MAGIC;
            if (lane < NBLK_T)
                v = __hip_atomic_load(&flags[b * NBLK_T + lane], __ATOMIC_ACQUIRE,
                                      __HIP_MEMORY_SCOPE_AGENT);
            done = __all(v == FLAG_MAGIC);
            if (!done) __builtin_amdgcn_s_sleep(8);
        }
    }
    __syncthreads();
    __threadfence();

    if (role >= B_) {
        // ---- mem reduction for b ----
        const int d = tid;
        float sum = 0.f;
        #pragma unroll
        for (int i = 0; i < NBLK_T; ++i)
            sum += mem_part[((size_t)b * NBLK_T + i) * D_ + d];
        mem[b * D_ + d] = sum;
        return;
    }

    // ---- affine scan s_t = a_t*s_{t-1} + u_t via shfl composition scan ----
    // (A,U) after (A1,U1) = (A*A1, A*U1+U). mem0 = 0 so entering state = U.
    const int base = b * T_;
    const int4 pv = reinterpret_cast<const int4*>(pad + base)[tid];
    const int4 uv = reinterpret_cast<const int4*>(upd + base)[tid];
    const float4 yv = reinterpret_cast<const float4*>(y + base)[tid];
    int g[4];
    g[0] = (pv.x == 0 && uv.x != 0) ? 1 : 0;
    g[1] = (pv.y == 0 && uv.y != 0) ? 1 : 0;
    g[2] = (pv.z == 0 && uv.z != 0) ? 1 : 0;
    g[3] = (pv.w == 0 && uv.w != 0) ? 1 : 0;
    const float yl[4] = {yv.x, yv.y, yv.z, yv.w};

    float av[4], uvv[4];
    float a_c = 1.f, u_c = 0.f;            // per-thread compose over 4 elems
    #pragma unroll
    for (int i = 0; i < 4; ++i) {
        float a = g[i] ? (1.f - EPS) : 1.f;
        float u = g[i] ? EPS * yl[i] : 0.f;   // y is stale where !g — selected out
        av[i] = a; uvv[i] = u;
        u_c = a * u_c + u;
        a_c = a * a_c;
    }

    float A = a_c, U = u_c;                // wave-inclusive composition scan
    #pragma unroll
    for (int off = 1; off <= 32; off <<= 1) {
        float A1 = __shfl_up(A, off);
        float U1 = __shfl_up(U, off);
        if (lane >= off) { U = A * U1 + U; A = A * A1; }
    }
    __shared__ float wA[16], wU[16];
    if (lane == 63) { wA[wave] = A; wU[wave] = U; }
    __syncthreads();
    if (wave == 0 && lane < 16) {          // scan 16 wave totals
        float A2 = wA[lane], U2 = wU[lane];
        #pragma unroll
        for (int off = 1; off <= 8; off <<= 1) {
            float A1 = __shfl_up(A2, off);
            float U1 = __shfl_up(U2, off);
            if (lane >= off) { U2 = A2 * U1 + U2; A2 = A2 * A1; }
        }
        wA[lane] = A2; wU[lane] = U2;
    }
    __syncthreads();
    float At = __shfl_up(A, 1), Ut = __shfl_up(U, 1);
    if (lane == 0) { At = 1.f; Ut = 0.f; }
    const float Uw = (wave > 0) ? wU[wave - 1] : 0.f;   // state entering wave
    float s = At * Uw + Ut;                             // state entering thread

    const int pl[4] = {pv.x, pv.y, pv.z, pv.w};
    float4 bv;
    float* bp = &bv.x;
    #pragma unroll
    for (int i = 0; i < 4; ++i) {
        s = av[i] * s + uvv[i];
        float bval;
        if (pl[i] != 0) {
            bval = 1.f;
        } else {
            bval = 1.f + tanhf(s);
            bval = fminf(fmaxf(bval, 0.8f), 1.2f);
        }
        bp[i] = bval;
    }
    reinterpret_cast<float4*>(bias + base)[tid] = bv;
}

extern "C" void kernel_launch(void* const* d_in, const int* in_sizes, int n_in,
                              void* d_out, int out_size, void* d_ws, size_t ws_size,
                              hipStream_t stream) {
    const float* x  = (const float*)d_in[0];   // write_signal (B,T,D) f32
    const int* pad  = (const int*)d_in[1];     // pad_mask (B,T)
    const int* upd  = (const int*)d_in[2];     // update_mask (B,T)
    const float* w  = (const float*)d_in[3];   // (D,) f32

    float* out  = (float*)d_out;
    float* bias = out;                 // B*T floats
    float* mem  = out + B_ * T_;       // B*D floats

    float* y        = (float*)d_ws;                    // B*T floats
    float* mem_part = y + B_ * T_;                     // B*NBLK_T*D floats
    unsigned* flags = (unsigned*)(mem_part + (size_t)B_ * NBLK_T * D_);  // 256

    fused_kernel<<<NPROD + 2 * B_, 1024, 0, stream>>>(
        x, w, pad, upd, y, mem_part, flags, bias, mem);
}

// Round 12
// 179.818 us; speedup vs baseline: 1.4318x; 1.4318x over previous
//
#include <hip/hip_runtime.h>

#define EPS 0.01f
#define B_ 8
#define T_ 4096
#define D_ 1024

// ---------------- Kernel A: fused alpha + y = x@w + per-block mem partials ----
// Per block: (1) global gate prefix scan over row b via wave-shfl (for alpha
// exponents), (2) block-local compaction of gated rows via __ballot so the 16
// waves split gated rows evenly, (3) one wave per compacted gated row.
// TCHUNK=128 -> 256 blocks (1/CU). Best measured config (R6: 180.9 us).
// Ledger: TCHUNK=64 occupancy retune HURT (R3 +11us); producer/consumer
// single-launch fusion HURT (R8 +77us, device-fence L2-writeback storms);
// x is L3-resident across graph replays (R8: FETCH 1.4MB on replay).
#define TCHUNK 128
#define NBLK_T (T_ / TCHUNK)   // 32
__global__ __launch_bounds__(1024) void main_pass_kernel(
    const float* __restrict__ x, const float* __restrict__ w,
    const int* __restrict__ pad, const int* __restrict__ upd,
    float* __restrict__ y, float* __restrict__ mem_part) {
    const int b = blockIdx.y;
    const int tbase = blockIdx.x * TCHUNK;
    const int tid = threadIdx.x;           // 0..1023
    const int wave = tid >> 6;             // 0..15
    const int lane = tid & 63;
    const int base = b * T_;

    __shared__ float alpha_s[TCHUNK];
    __shared__ int wtot[16];
    __shared__ int idx_s[TCHUNK];          // compacted gated row indices
    __shared__ int cnt_s[2];               // per-wave gated counts (waves 0,1)
    __shared__ int n_s;                    // total gated in this block

    // ---- per-thread gate bits for the GLOBAL scan (4 t's per thread) ----
    const int4 pv = reinterpret_cast<const int4*>(pad + base)[tid];
    const int4 uv = reinterpret_cast<const int4*>(upd + base)[tid];
    int g[4];
    g[0] = (pv.x == 0 && uv.x != 0) ? 1 : 0;
    g[1] = (pv.y == 0 && uv.y != 0) ? 1 : 0;
    g[2] = (pv.z == 0 && uv.z != 0) ? 1 : 0;
    g[3] = (pv.w == 0 && uv.w != 0) ? 1 : 0;
    const int cnt = g[0] + g[1] + g[2] + g[3];

    int inc = cnt;                          // wave-inclusive scan, no barriers
    #pragma unroll
    for (int off = 1; off <= 32; off <<= 1) {
        int n = __shfl_up(inc, off);
        if (lane >= off) inc += n;
    }
    if (lane == 63) wtot[wave] = inc;

    // ---- block-local compaction (threads 0..127 own t = tbase + tid) ----
    int rank1 = -1;                         // wave1's deferred rank
    if (tid < TCHUNK) {
        const int t = tbase + tid;
        const int gl = (pad[base + t] == 0 && upd[base + t] != 0) ? 1 : 0;
        const unsigned long long m = __ballot(gl);
        const int rank = __popcll(m & ((1ull << lane) - 1ull));
        if (lane == 0) cnt_s[wave] = __popcll(m);
        if (gl) {
            if (wave == 0) idx_s[rank] = tid;   // offset 0
            else           rank1 = rank;        // needs cnt_s[0], after barrier
        }
    }
    __syncthreads();

    if (wave == 0 && lane < 16) {           // scan the 16 wave totals
        int iv = wtot[lane];
        #pragma unroll
        for (int off = 1; off <= 8; off <<= 1) {
            int n = __shfl_up(iv, off);
            if (lane >= off) iv += n;
        }
        wtot[lane] = iv;
    }
    if (rank1 >= 0) idx_s[cnt_s[0] + rank1] = tid;   // wave1 compaction writes
    if (tid == 0) n_s = cnt_s[0] + cnt_s[1];
    __syncthreads();

    // ---- alpha for this block's rows ----
    {
        const int total = wtot[15];
        int c = (wave > 0 ? wtot[wave - 1] : 0) + inc - cnt;  // exclusive prefix
        const float L = -0.014499569695115089f;  // log2(0.99)
        #pragma unroll
        for (int i = 0; i < 4; ++i) {
            const int t = 4 * tid + i;
            c += g[i];
            if (t >= tbase && t < tbase + TCHUNK)
                alpha_s[t - tbase] = g[i] ? EPS * exp2f((float)(total - c) * L) : 0.f;
        }
    }
    __syncthreads();
    const int n_gated = n_s;

    float4 wv[4];
    #pragma unroll
    for (int k = 0; k < 4; ++k)
        wv[k] = *reinterpret_cast<const float4*>(w + k * 256 + lane * 4);

    float4 acc[4];
    #pragma unroll
    for (int k = 0; k < 4; ++k) acc[k] = make_float4(0.f, 0.f, 0.f, 0.f);

    // ---- balanced main loop: wave j handles compacted rows j, j+16, ... ----
    #pragma unroll 2
    for (int j = wave; j < n_gated; j += 16) {
        const int r = idx_s[j];
        const float al = alpha_s[r];
        const int t = tbase + r;
        const float* rowp = x + ((size_t)b * T_ + t) * D_;
        float dot = 0.f;
        #pragma unroll
        for (int k = 0; k < 4; ++k) {
            float4 v = *reinterpret_cast<const float4*>(rowp + k * 256 + lane * 4);
            dot += v.x * wv[k].x + v.y * wv[k].y + v.z * wv[k].z + v.w * wv[k].w;
            acc[k].x += al * v.x;
            acc[k].y += al * v.y;
            acc[k].z += al * v.z;
            acc[k].w += al * v.w;
        }
        #pragma unroll
        for (int off = 32; off >= 1; off >>= 1)
            dot += __shfl_xor(dot, off);
        if (lane == 0) y[b * T_ + t] = dot;
    }

    // Block-level reduction of mem partials: [wave][d] layout, then each
    // thread sums one d over the 16 waves (conflict-free column reads).
    __shared__ float part[16][D_];         // 64 KiB
    #pragma unroll
    for (int k = 0; k < 4; ++k)
        *reinterpret_cast<float4*>(&part[wave][k * 256 + lane * 4]) = acc[k];
    __syncthreads();
    float sum = 0.f;
    #pragma unroll
    for (int w2 = 0; w2 < 16; ++w2) sum += part[w2][tid];
    mem_part[((size_t)b * NBLK_T + blockIdx.x) * D_ + tid] = sum;
}

// ---------------- Kernel B (fused): blocks 0..7 = affine scan -> bias,
//                  blocks 8..15 = reduce mem partials -> mem ----------------
// Affine scan s_t = a_t*s_{t-1} + u_t via shfl composition scan:
// (A,U) after (A1,U1) = (A*A1, A*U1 + U). mem0 = 0 so entering state = U.
__global__ __launch_bounds__(1024) void finalize_kernel(
    const float* __restrict__ y, const int* __restrict__ pad,
    const int* __restrict__ upd, const float* __restrict__ mem_part,
    float* __restrict__ bias, float* __restrict__ mem) {
    if (blockIdx.x >= B_) {
        const int b = blockIdx.x - B_;
        const int d = threadIdx.x;
        float sum = 0.f;
        #pragma unroll
        for (int i = 0; i < NBLK_T; ++i)
            sum += mem_part[((size_t)b * NBLK_T + i) * D_ + d];
        mem[b * D_ + d] = sum;
        return;
    }

    const int b = blockIdx.x;
    const int tid = threadIdx.x;            // 0..1023
    const int wave = tid >> 6;
    const int lane = tid & 63;
    const int base = b * T_;

    const int4 pv = reinterpret_cast<const int4*>(pad + base)[tid];
    const int4 uv = reinterpret_cast<const int4*>(upd + base)[tid];
    const float4 yv = reinterpret_cast<const float4*>(y + base)[tid];
    int g[4];
    g[0] = (pv.x == 0 && uv.x != 0) ? 1 : 0;
    g[1] = (pv.y == 0 && uv.y != 0) ? 1 : 0;
    g[2] = (pv.z == 0 && uv.z != 0) ? 1 : 0;
    g[3] = (pv.w == 0 && uv.w != 0) ? 1 : 0;
    const float yl[4] = {yv.x, yv.y, yv.z, yv.w};

    float av[4], uvv[4];
    float a_c = 1.f, u_c = 0.f;            // per-thread compose over 4 elems
    #pragma unroll
    for (int i = 0; i < 4; ++i) {
        float a = g[i] ? (1.f - EPS) : 1.f;
        float u = g[i] ? EPS * yl[i] : 0.f;   // y is stale where !g — selected out
        av[i] = a; uvv[i] = u;
        u_c = a * u_c + u;
        a_c = a * a_c;
    }

    // wave-inclusive composition scan (no barriers)
    float A = a_c, U = u_c;
    #pragma unroll
    for (int off = 1; off <= 32; off <<= 1) {
        float A1 = __shfl_up(A, off);
        float U1 = __shfl_up(U, off);
        if (lane >= off) { U = A * U1 + U; A = A * A1; }
    }
    __shared__ float wA[16], wU[16];
    if (lane == 63) { wA[wave] = A; wU[wave] = U; }
    __syncthreads();
    if (wave == 0 && lane < 16) {          // scan 16 wave totals
        float A2 = wA[lane], U2 = wU[lane];
        #pragma unroll
        for (int off = 1; off <= 8; off <<= 1) {
            float A1 = __shfl_up(A2, off);
            float U1 = __shfl_up(U2, off);
            if (lane >= off) { U2 = A2 * U1 + U2; A2 = A2 * A1; }
        }
        wA[lane] = A2; wU[lane] = U2;
    }
    __syncthreads();
    // thread-exclusive within-wave compose
    float At = __shfl_up(A, 1), Ut = __shfl_up(U, 1);
    if (lane == 0) { At = 1.f; Ut = 0.f; }
    const float Uw = (wave > 0) ? wU[wave - 1] : 0.f;   // state entering this wave
    float s = At * Uw + Ut;                             // state entering this thread

    const int pl[4] = {pv.x, pv.y, pv.z, pv.w};
    float4 bv;
    float* bp = &bv.x;
    #pragma unroll
    for (int i = 0; i < 4; ++i) {
        s = av[i] * s + uvv[i];
        float bval;
        if (pl[i] != 0) {
            bval = 1.f;
        } else {
            bval = 1.f + tanhf(s);
            bval = fminf(fmaxf(bval, 0.8f), 1.2f);
        }
        bp[i] = bval;
    }
    reinterpret_cast<float4*>(bias + base)[tid] = bv;
}

extern "C" void kernel_launch(void* const* d_in, const int* in_sizes, int n_in,
                              void* d_out, int out_size, void* d_ws, size_t ws_size,
                              hipStream_t stream) {
    const float* x  = (const float*)d_in[0];   // write_signal (B,T,D) f32
    const int* pad  = (const int*)d_in[1];     // pad_mask (B,T)
    const int* upd  = (const int*)d_in[2];     // update_mask (B,T)
    const float* w  = (const float*)d_in[3];   // (D,) f32

    float* out  = (float*)d_out;
    float* bias = out;                 // B*T floats
    float* mem  = out + B_ * T_;       // B*D floats

    float* y        = (float*)d_ws;             // B*T floats
    float* mem_part = y + B_ * T_;              // B*NBLK_T*D floats (1 MiB)

    dim3 gridA(NBLK_T, B_);
    main_pass_kernel<<<gridA, 1024, 0, stream>>>(x, w, pad, upd, y, mem_part);
    finalize_kernel<<<2 * B_, 1024, 0, stream>>>(y, pad, upd, mem_part, bias, mem);
}